// Round 8
// baseline (242.046 us; speedup 1.0000x reference)
//
#include <hip/hip_runtime.h>

#define TT 4096
#define CCH 768
#define HH 64
#define BBA 8
#define MROWS (BBA*TT)   // 32768
#define NCHUNK_PB 288    // chunks per batch at S<=8

typedef __attribute__((ext_vector_type(8))) short short8;
typedef __attribute__((ext_vector_type(4))) float floatx4;
#if __has_builtin(__builtin_amdgcn_cvt_pk_bf16_f32)
typedef __attribute__((ext_vector_type(2))) __bf16 bf16x2;
#endif

__device__ inline ushort f2bf(float f) {
    union { float f; unsigned u; } v; v.f = f;
    unsigned r = v.u + 0x7fffu + ((v.u >> 16) & 1u);   // RNE
    return (ushort)(r >> 16);
}

__device__ inline float bf2f(ushort h) {
    union { unsigned u; float f; } v; v.u = ((unsigned)h) << 16;
    return v.f;
}

__device__ inline unsigned pk_bf16(float a, float b) {
#if __has_builtin(__builtin_amdgcn_cvt_pk_bf16_f32)
    union { bf16x2 v; unsigned u; } cv;
    cv.v = __builtin_amdgcn_cvt_pk_bf16_f32(a, b);
    return cv.u;
#else
    union { float f; unsigned u; } x, y; x.f = a; y.f = b;
    unsigned ra = x.u + 0x7fffu + ((x.u >> 16) & 1u);
    unsigned rb = y.u + 0x7fffu + ((y.u >> 16) & 1u);
    return (ra >> 16) | (rb & 0xffff0000u);
#endif
}

__device__ inline float fast_exp2(float x) {
#if __has_builtin(__builtin_amdgcn_exp2f)
    return __builtin_amdgcn_exp2f(x);
#else
    return exp2f(x);
#endif
}

// ---- Kernel 1: Wt[3][64][768] bf16, n-major, via LDS transpose.
// Wq is PRE-SCALED by 768^-0.5 * log2(e): attn's QK^T emerges in exp2 domain
// with no per-element multiply.
__global__ __launch_bounds__(256) void wt_kernel(const float* __restrict__ Wq,
                                                 const float* __restrict__ Wk,
                                                 const float* __restrict__ Wv,
                                                 ushort* __restrict__ wt) {
    __shared__ float tile[64][65];
    const int m = blockIdx.x / 12, kt = blockIdx.x % 12;
    const float* W = (m == 0) ? Wq : (m == 1) ? Wk : Wv;
    const float scl = (m == 0) ? 0.052058773f : 1.0f;   // 768^-0.5 * log2(e)
    const int n = threadIdx.x & 63, r0 = threadIdx.x >> 6;
#pragma unroll
    for (int i = 0; i < 16; ++i) {
        int k = r0 * 16 + i;
        tile[k][n] = W[(kt * 64 + k) * 64 + n] * scl;
    }
    __syncthreads();
    const int k2 = threadIdx.x & 63, n2 = threadIdx.x >> 6;
#pragma unroll
    for (int i = 0; i < 16; ++i) {
        int nn = n2 * 16 + i;
        wt[(m * 64 + nn) * 768 + kt * 64 + k2] = f2bf(tile[k2][nn]);
    }
}

// ---- Kernel 2: QKV projection v8 — BK=64, 1024 blocks x 32 rows (4 blocks/CU).
// Waves {0,1}: rows 0-15/16-31, nt 0-5; waves {2,3}: same rows, nt 6-11.
// Depth-1 register prefetch issued right after the barrier, before the MFMA span.
__global__ __launch_bounds__(256) void proj_kernel(const float* __restrict__ x,
                                                   const ushort* __restrict__ wt,
                                                   ushort* __restrict__ qb,
                                                   ushort* __restrict__ kb,
                                                   ushort* __restrict__ vtg) {
    __shared__ ushort xs[32 * 72];      // 32 rows x 64 k (bf16)
    __shared__ ushort ws[192 * 72];     // 192 cols x 64 k (bf16)
    const int tid = threadIdx.x;
    const int w = tid >> 6, lane = tid & 63, c = lane & 15, qd = lane >> 4;
    const int rbase = blockIdx.x * 32;
    const int rowh = (w & 1) * 16;      // wave's row half
    const int nbase = (w >> 1) * 6;     // wave's nt base
    const int xr = tid >> 3;            // x staging row 0..31
    const int xc = (tid & 7) * 8;       // x staging k-offset (8 floats)
    const int swr = tid >> 2;           // W staging row 0..63 (+64*i)
    const int swc = (tid & 3) * 16;     // W staging k-offset (16 bf16)

    floatx4 acc[6];
#pragma unroll
    for (int nt = 0; nt < 6; ++nt) acc[nt] = (floatx4){0.f, 0.f, 0.f, 0.f};

    const float*  xsrc  = &x[(size_t)(rbase + xr) * CCH + xc];
    const ushort* wsrc0 = &wt[(size_t)(0 * 64 + swr) * CCH + swc];
    const ushort* wsrc1 = &wt[(size_t)(1 * 64 + swr) * CCH + swc];
    const ushort* wsrc2 = &wt[(size_t)(2 * 64 + swr) * CCH + swc];

    // prefetch registers: x 8 floats, W 3x32 bf16
    float4 xr0, xr1;
    short8 wr[6];
    xr0 = *(const float4*)&xsrc[0]; xr1 = *(const float4*)&xsrc[4];
    wr[0] = *(const short8*)&wsrc0[0]; wr[1] = *(const short8*)&wsrc0[8];
    wr[2] = *(const short8*)&wsrc1[0]; wr[3] = *(const short8*)&wsrc1[8];
    wr[4] = *(const short8*)&wsrc2[0]; wr[5] = *(const short8*)&wsrc2[8];

    for (int kc = 0; kc < CCH; kc += 64) {
        uint4 s0;
        s0.x = pk_bf16(xr0.x, xr0.y); s0.y = pk_bf16(xr0.z, xr0.w);
        s0.z = pk_bf16(xr1.x, xr1.y); s0.w = pk_bf16(xr1.z, xr1.w);
        *(uint4*)&xs[xr * 72 + xc] = s0;
        *(short8*)&ws[(0 * 64 + swr) * 72 + swc]     = wr[0];
        *(short8*)&ws[(0 * 64 + swr) * 72 + swc + 8] = wr[1];
        *(short8*)&ws[(1 * 64 + swr) * 72 + swc]     = wr[2];
        *(short8*)&ws[(1 * 64 + swr) * 72 + swc + 8] = wr[3];
        *(short8*)&ws[(2 * 64 + swr) * 72 + swc]     = wr[4];
        *(short8*)&ws[(2 * 64 + swr) * 72 + swc + 8] = wr[5];
        __syncthreads();
        if (kc + 64 < CCH) {    // issue next chunk's loads BEFORE the compute span
            xr0 = *(const float4*)&xsrc[kc + 64];
            xr1 = *(const float4*)&xsrc[kc + 68];
            wr[0] = *(const short8*)&wsrc0[kc + 64]; wr[1] = *(const short8*)&wsrc0[kc + 72];
            wr[2] = *(const short8*)&wsrc1[kc + 64]; wr[3] = *(const short8*)&wsrc1[kc + 72];
            wr[4] = *(const short8*)&wsrc2[kc + 64]; wr[5] = *(const short8*)&wsrc2[kc + 72];
        }
        short8 a0 = *(const short8*)&xs[(rowh + c) * 72 + qd * 8];
        short8 a1 = *(const short8*)&xs[(rowh + c) * 72 + 32 + qd * 8];
#pragma unroll
        for (int nt = 0; nt < 6; ++nt) {
            short8 b0 = *(const short8*)&ws[((nbase + nt) * 16 + c) * 72 + qd * 8];
            short8 b1 = *(const short8*)&ws[((nbase + nt) * 16 + c) * 72 + 32 + qd * 8];
            acc[nt] = __builtin_amdgcn_mfma_f32_16x16x32_bf16(a0, b0, acc[nt], 0, 0, 0);
            acc[nt] = __builtin_amdgcn_mfma_f32_16x16x32_bf16(a1, b1, acc[nt], 0, 0, 0);
        }
        __syncthreads();
    }
    // epilogue: q,k row-major; v transposed [b][h][t] with 8B vector stores
    const int bb = rbase >> 12;
#pragma unroll
    for (int nt = 0; nt < 6; ++nt) {
        int ncol = (nbase + nt) * 16 + c;
        if (ncol < 128) {
            ushort* dst = (ncol < 64) ? qb : kb;
            int h = ncol & 63;
#pragma unroll
            for (int r = 0; r < 4; ++r) {
                int rg = rbase + rowh + qd * 4 + r;
                dst[(size_t)rg * 64 + h] = f2bf(acc[nt][r]);
            }
        } else {
            int h = ncol - 128;
            int trow = (rbase & 4095) + rowh + qd * 4;
            uint2 val;
            val.x = pk_bf16(acc[nt][0], acc[nt][1]);
            val.y = pk_bf16(acc[nt][2], acc[nt][3]);
            *(uint2*)&vtg[((size_t)(bb * 64 + h)) * 4096 + trow] = val;
        }
    }
}

// ---- Kernel 3: chunked flash attention, FIXED-REFERENCE softmax (m=0),
// Q pre-scaled (scores emerge in exp2 domain). ----
__global__ __launch_bounds__(256) void attn_kernel(const ushort* __restrict__ qb,
                                                   const ushort* __restrict__ kb,
                                                   const ushort* __restrict__ vtg,
                                                   float* __restrict__ out,
                                                   ushort* __restrict__ Opart,
                                                   float* __restrict__ Ol,
                                                   int mode) {
    __shared__ ushort Ks[64 * 72];      // [key][dim]
    __shared__ ushort Vt[64 * 72];      // [dim][key]
    __shared__ ushort Pl[4][1024];
    const int tid = threadIdx.x;
    const int w = tid >> 6, lane = tid & 63, c = lane & 15, qd = lane >> 4;
    const int bx = blockIdx.x;
    const int b = bx & 7, craw = bx >> 3;

    int qt, chunk, nch, cix;
    if (mode == 0) {
        qt = 63 - craw; nch = 1; chunk = 0; cix = qt;
    } else {
        cix = (NCHUNK_PB - 1) - craw;           // big chunks dispatch first
        int idx, s;
        if      (cix <   8) { idx = 0; s =   0; }
        else if (cix <  24) { idx = 1; s =   8; }
        else if (cix <  48) { idx = 2; s =  24; }
        else if (cix <  80) { idx = 3; s =  48; }
        else if (cix < 120) { idx = 4; s =  80; }
        else if (cix < 168) { idx = 5; s = 120; }
        else if (cix < 224) { idx = 6; s = 168; }
        else                { idx = 7; s = 224; }
        nch = idx + 1;
        int d = cix - s;
        qt = (idx << 3) + d / nch;
        chunk = d - (d / nch) * nch;
    }
    const int n = qt + 1;
    const int kbeg = chunk * n / nch;
    const int kend = (chunk + 1) * n / nch;
    const bool direct = (nch == 1);
    const int qbase = qt * 64;

    const size_t growq = (size_t)(b * TT + qbase + w * 16 + c);
    short8 qf0 = *(const short8*)&qb[growq * 64 + qd * 8];
    short8 qf1 = *(const short8*)&qb[growq * 64 + 32 + qd * 8];
    floatx4 o[4];
#pragma unroll
    for (int nt = 0; nt < 4; ++nt) o[nt] = (floatx4){0.f, 0.f, 0.f, 0.f};
    float lsum = 0.f;                   // per-lane partial; reduced after loop

    const int sr = tid >> 2;            // K staging: key row
    const int sk = (tid & 3) * 16;      // K staging: dim offset
    const int vd = tid >> 2;            // V staging: dim row
    const int vk = (tid & 3) * 16;      // V staging: key offset
    const ushort* kbb = &kb[(size_t)(b * TT) * 64];
    const ushort* vbb = &vtg[(size_t)(b * 64) * 4096];

    short8 k0, k1, v0, v1;
    {
        const ushort* srcK = &kbb[((size_t)(kbeg * 64 + sr)) * 64 + sk];
        k0 = *(const short8*)srcK; k1 = *(const short8*)(srcK + 8);
        const ushort* srcV = &vbb[(size_t)vd * 4096 + kbeg * 64 + vk];
        v0 = *(const short8*)srcV; v1 = *(const short8*)(srcV + 8);
    }

    for (int kt = kbeg; kt < kend; ++kt) {
        __syncthreads();
        *(short8*)&Ks[sr * 72 + sk] = k0;
        *(short8*)&Ks[sr * 72 + sk + 8] = k1;
        *(short8*)&Vt[vd * 72 + vk] = v0;
        *(short8*)&Vt[vd * 72 + vk + 8] = v1;
        __syncthreads();
        if (kt + 1 < kend) {
            const ushort* srcK = &kbb[((size_t)((kt + 1) * 64 + sr)) * 64 + sk];
            k0 = *(const short8*)srcK; k1 = *(const short8*)(srcK + 8);
            const ushort* srcV = &vbb[(size_t)vd * 4096 + (kt + 1) * 64 + vk];
            v0 = *(const short8*)srcV; v1 = *(const short8*)(srcV + 8);
        }
        floatx4 st[4];
#pragma unroll
        for (int mt = 0; mt < 4; ++mt) {
            short8 kf0 = *(const short8*)&Ks[(mt * 16 + c) * 72 + qd * 8];
            short8 kf1 = *(const short8*)&Ks[(mt * 16 + c) * 72 + 32 + qd * 8];
            st[mt] = (floatx4){0.f, 0.f, 0.f, 0.f};
            st[mt] = __builtin_amdgcn_mfma_f32_16x16x32_bf16(kf0, qf0, st[mt], 0, 0, 0);
            st[mt] = __builtin_amdgcn_mfma_f32_16x16x32_bf16(kf1, qf1, st[mt], 0, 0, 0);
        }
        float p[16];
#pragma unroll
        for (int mt = 0; mt < 4; ++mt)
#pragma unroll
            for (int r = 0; r < 4; ++r)
                p[mt * 4 + r] = st[mt][r];              // already exp2-domain
        if (kt == qt) {                                  // diagonal tile only
            const int thr = w * 16 + c;
#pragma unroll
            for (int mt = 0; mt < 4; ++mt)
#pragma unroll
                for (int r = 0; r < 4; ++r) {
                    int kl = mt * 16 + qd * 4 + r;
                    if (kl > thr) p[mt * 4 + r] = -1e30f;
                }
        }
#pragma unroll
        for (int i = 0; i < 16; ++i) { p[i] = fast_exp2(p[i]); lsum += p[i]; }
#pragma unroll
        for (int mt = 0; mt < 4; ++mt) {
            uint2 pk;
            pk.x = pk_bf16(p[mt * 4 + 0], p[mt * 4 + 1]);
            pk.y = pk_bf16(p[mt * 4 + 2], p[mt * 4 + 3]);
            int g = 2 * mt + (qd >> 1);
            int off = c * 64 + ((g ^ (c & 7)) << 3) + ((qd & 1) << 2);
            *(uint2*)&Pl[w][off] = pk;
        }
        short8 pf0 = *(const short8*)&Pl[w][c * 64 + (((qd) ^ (c & 7)) << 3)];
        short8 pf1 = *(const short8*)&Pl[w][c * 64 + (((4 + qd) ^ (c & 7)) << 3)];
#pragma unroll
        for (int nt = 0; nt < 4; ++nt) {
            short8 vf0 = *(const short8*)&Vt[(nt * 16 + c) * 72 + qd * 8];
            short8 vf1 = *(const short8*)&Vt[(nt * 16 + c) * 72 + 32 + qd * 8];
            o[nt] = __builtin_amdgcn_mfma_f32_16x16x32_bf16(pf0, vf0, o[nt], 0, 0, 0);
            o[nt] = __builtin_amdgcn_mfma_f32_16x16x32_bf16(pf1, vf1, o[nt], 0, 0, 0);
        }
    }

    // single post-loop l reduction across the 4 key-quads
    float l_run = lsum;
    l_run += __shfl_xor(l_run, 16);
    l_run += __shfl_xor(l_run, 32);

    if (direct) {
#pragma unroll
        for (int r = 0; r < 4; ++r) {
            float lr = __shfl(l_run, qd * 4 + r);
            float inv = 1.f / lr;
            size_t rowg = (size_t)(b * TT) + qbase + w * 16 + qd * 4 + r;
#pragma unroll
            for (int nt = 0; nt < 4; ++nt)
                out[rowg * 64 + nt * 16 + c] = o[nt][r] * inv;
        }
    } else {
        const int slot = b * NCHUNK_PB + cix;
        ushort* Od = Opart + (size_t)slot * 4096;
#pragma unroll
        for (int r = 0; r < 4; ++r) {
            int row = w * 16 + qd * 4 + r;
#pragma unroll
            for (int nt = 0; nt < 4; ++nt)
                Od[row * 64 + nt * 16 + c] = f2bf(o[nt][r]);
        }
        if (qd == 0)
            Ol[(size_t)slot * 64 + w * 16 + c] = l_run;
    }
}

// ---- Kernel 4: combine partials (fixed m=0 reference: plain sums) ----
__global__ __launch_bounds__(256) void combine_kernel(const ushort* __restrict__ Opart,
                                                      const float* __restrict__ Ol,
                                                      float* __restrict__ out) {
    const int b = blockIdx.x & 7;
    const int qt = 8 + (blockIdx.x >> 3);
    const int idx = qt >> 3;   // 1..7
    int s;
    if      (idx == 1) s = 8;
    else if (idx == 2) s = 24;
    else if (idx == 3) s = 48;
    else if (idx == 4) s = 80;
    else if (idx == 5) s = 120;
    else if (idx == 6) s = 168;
    else               s = 224;
    const int nch = idx + 1;
    const int c0 = s + (qt - (idx << 3)) * nch;
    const size_t slot0 = (size_t)(b * NCHUNK_PB + c0);
    const int t = threadIdx.x;
    const int col = t & 63, r0 = t >> 6;

    for (int rr = 0; rr < 16; ++rr) {
        int row = (rr << 2) + r0;
        float S = 0.f, A = 0.f;
        for (int i = 0; i < nch; ++i) {
            S += Ol[(slot0 + i) * 64 + row];
            A += bf2f(Opart[(slot0 + i) * 4096 + row * 64 + col]);
        }
        out[((size_t)(b * TT) + qt * 64 + row) * 64 + col] = A / S;
    }
}

extern "C" void kernel_launch(void* const* d_in, const int* in_sizes, int n_in,
                              void* d_out, int out_size, void* d_ws, size_t ws_size,
                              hipStream_t stream) {
    const float* x  = (const float*)d_in[0];
    const float* Wk = (const float*)d_in[1];
    const float* Wq = (const float*)d_in[2];
    const float* Wv = (const float*)d_in[3];
    float* out = (float*)d_out;

    // ws: q,k bf16 [32768][64]; v^T bf16 [8][64][4096]; Wt; bf16 partials + l
    ushort* qbuf = (ushort*)d_ws;
    ushort* kbuf = qbuf + (size_t)MROWS * 64;
    ushort* vbuf = kbuf + (size_t)MROWS * 64;
    ushort* wt   = vbuf + (size_t)MROWS * 64;
    const size_t base = (size_t)MROWS * 64 * 3 * 2 + (size_t)3 * 64 * CCH * 2;  // 12,877,824
    ushort* Opart = (ushort*)((char*)d_ws + base);
    float*  Ol    = (float*)((char*)d_ws + base + (size_t)BBA * NCHUNK_PB * 4096 * 2);
    const size_t need = base + (size_t)BBA * NCHUNK_PB * 4096 * 2
                             + (size_t)BBA * NCHUNK_PB * 64 * 4;   // ~32.4 MB
    const int split = (ws_size >= need) ? 1 : 0;

    wt_kernel<<<36, 256, 0, stream>>>(Wq, Wk, Wv, wt);
    proj_kernel<<<MROWS / 32, 256, 0, stream>>>(x, wt, qbuf, kbuf, vbuf);
    if (split) {
        attn_kernel<<<BBA * NCHUNK_PB, 256, 0, stream>>>(qbuf, kbuf, vbuf, out, Opart, Ol, 1);
        combine_kernel<<<BBA * 56, 256, 0, stream>>>(Opart, Ol, out);
    } else {
        attn_kernel<<<BBA * 64, 256, 0, stream>>>(qbuf, kbuf, vbuf, out, Opart, Ol, 0);
    }
}